// Round 1
// baseline (3369.868 us; speedup 1.0000x reference)
//
#include <hip/hip_runtime.h>
#include <hip/hip_bf16.h>
#include <stdint.h>

typedef __bf16 bf16_t;
typedef __attribute__((ext_vector_type(8))) __bf16 bf16x8;
typedef __attribute__((ext_vector_type(4))) float f32x4;

#define B_N 2048
#define T_N 96
#define I_N 64
#define H_N 1024
#define O_N 256
#define KTOT 1088   /* H + I */
#define NG   4096   /* 4*H  */

// ---------- helpers ----------
__device__ __forceinline__ void gload16(const void* g, void* l) {
  // global -> LDS direct, 16B per lane. LDS dest must be wave-uniform base
  // (HW adds lane*16).
  __builtin_amdgcn_global_load_lds(
      (const __attribute__((address_space(1))) uint32_t*)(uintptr_t)g,
      (__attribute__((address_space(3))) uint32_t*)(uintptr_t)l,
      16, 0, 0);
}

__device__ __forceinline__ float sigmoid_(float x) {
  return 1.0f / (1.0f + __expf(-x));
}
__device__ __forceinline__ float tanh_(float x) {
  float ax = fabsf(x);
  float e  = __expf(-2.0f * ax);     // (0,1], never overflows
  float t  = (1.0f - e) / (1.0f + e);
  return copysignf(t, x);
}

// ---------- prep kernels ----------
__global__ void prep_weights(const float* __restrict__ Wi_h, const float* __restrict__ Wf_h,
                             const float* __restrict__ Wm_h, const float* __restrict__ Wo_h,
                             const float* __restrict__ Wi_x, const float* __restrict__ Wf_x,
                             const float* __restrict__ Wm_x, const float* __restrict__ Wo_x,
                             bf16_t* __restrict__ Bmat) {
  int idx = blockIdx.x * blockDim.x + threadIdx.x;
  const int total = NG * KTOT;
  if (idx >= total) return;
  int r = idx / KTOT;
  int k = idx - r * KTOT;
  int gate = r >> 10;       // 0:i 1:f 2:m 3:o
  int j    = r & 1023;
  const float* Wh[4] = {Wi_h, Wf_h, Wm_h, Wo_h};
  const float* Wx[4] = {Wi_x, Wf_x, Wm_x, Wo_x};
  float v = (k < H_N) ? Wh[gate][j * H_N + k] : Wx[gate][j * I_N + (k - H_N)];
  Bmat[idx] = (bf16_t)v;
}

__global__ void prep_misc(const float* __restrict__ bi, const float* __restrict__ bf_,
                          const float* __restrict__ bm, const float* __restrict__ bo,
                          const float* __restrict__ Wout, float* __restrict__ bb_all,
                          bf16_t* __restrict__ Wout_b) {
  int idx = blockIdx.x * blockDim.x + threadIdx.x;
  if (idx < NG) {
    int gate = idx >> 10, j = idx & 1023;
    const float* bp[4] = {bi, bf_, bm, bo};
    bb_all[idx] = bp[gate][j];
  }
  if (idx < O_N * H_N) Wout_b[idx] = (bf16_t)Wout[idx];
}

__global__ void prep_seq(const float4* __restrict__ seq4, bf16_t* __restrict__ seqb,
                         bf16_t* __restrict__ h0, float* __restrict__ c0) {
  int idx = blockIdx.x * blockDim.x + threadIdx.x;
  const int n4 = (B_N * T_N * I_N) / 4;
  if (idx < n4) {
    float4 v = seq4[idx];
    union { bf16_t b[4]; uint2 u; } pk;
    pk.b[0] = (bf16_t)v.x; pk.b[1] = (bf16_t)v.y;
    pk.b[2] = (bf16_t)v.z; pk.b[3] = (bf16_t)v.w;
    *reinterpret_cast<uint2*>(seqb + (size_t)idx * 4) = pk.u;
  }
  const int nh = B_N * H_N;
  if (idx < nh) {
    h0[idx] = (bf16_t)0.0f;
    c0[idx] = 0.0f;
  }
}

// ---------- fused LSTM step: g = [h | x_t] @ W'^T + b ; gates; c,h update ----------
// Block: 128 batch rows x 32 hidden units (x 4 gates => 128 output cols).
// Grid: 512 linear blocks, XCD-rect swizzled into (bx in 0..15, by in 0..31).
__global__ __launch_bounds__(256, 2) void lstm_step(
    const bf16_t* __restrict__ Bmat,   // [4H][KTOT]
    const float*  __restrict__ bb,     // [4H]
    const bf16_t* __restrict__ seqb,   // [B][T][I]
    const bf16_t* __restrict__ h_in,   // [B][H]
    bf16_t* __restrict__ h_out,        // [B][H]
    float*  __restrict__ c_buf,        // [B][H]
    int t) {
  __shared__ char smem[65536];
  bf16_t* A_lds = (bf16_t*)smem;             // [128][64]
  bf16_t* B_lds = (bf16_t*)(smem + 16384);   // [128][64]
  float*  g_lds = (float*)smem;              // [128][128] (reused after K-loop)

  const int tid  = threadIdx.x;
  const int wid  = tid >> 6;
  const int lane = tid & 63;

  // XCD-rect swizzle: 8 XCDs as 2x4 chunks of the 16x32 (bx,by) grid,
  // each XCD gets an 8x8 rect -> its weight slice (4 by-groups) stays L2-hot.
  {
  }
  const int bid = blockIdx.x;                 // 0..511
  const int xcd = bid & 7;
  const int r   = bid >> 3;                   // 0..63
  const int bx  = (xcd & 1) * 8 + (r & 7);    // 0..15 (M group)
  const int by  = (xcd >> 1) * 8 + (r >> 3);  // 0..31 (unit group)

  const int bm0 = bx * 128;
  const int j0  = by * 32;

  const int wr = wid >> 1, wc = wid & 1;      // wave covers 64x64 of 128x128

  f32x4 acc[4][4];
#pragma unroll
  for (int m = 0; m < 4; ++m)
#pragma unroll
    for (int n = 0; n < 4; ++n)
#pragma unroll
      for (int e = 0; e < 4; ++e) acc[m][n][e] = 0.0f;

  const int srow = tid >> 3;         // 0..31
  const int scol = (tid & 7) * 8;    // 0..56

  // virtual B rows for the 4 staging chunks: n = it*32 + srow in 0..127
  int brow[4];
#pragma unroll
  for (int it = 0; it < 4; ++it) {
    int n = it * 32 + srow;
    int gate = n >> 5, u = n & 31;
    brow[it] = (gate << 10) + j0 + u;
  }

  for (int kt = 0; kt < 17; ++kt) {
    const int k0 = kt * 64;
    if (kt < 16) {
#pragma unroll
      for (int it = 0; it < 4; ++it) {
        int row = it * 32 + srow;
        const bf16_t* gp = h_in + (size_t)(bm0 + row) * H_N + k0 + scol;
        gload16(gp, (char*)A_lds + (size_t)(it * 2048 + wid * 512) * 2);
      }
    } else {
#pragma unroll
      for (int it = 0; it < 4; ++it) {
        int row = it * 32 + srow;
        const bf16_t* gp = seqb + (size_t)(bm0 + row) * (T_N * I_N) + t * I_N + scol;
        gload16(gp, (char*)A_lds + (size_t)(it * 2048 + wid * 512) * 2);
      }
    }
#pragma unroll
    for (int it = 0; it < 4; ++it) {
      const bf16_t* gp = Bmat + (size_t)brow[it] * KTOT + k0 + scol;
      gload16(gp, (char*)B_lds + (size_t)(it * 2048 + wid * 512) * 2);
    }
    __syncthreads();   // drains vmcnt (global_load_lds) + makes tiles visible

    const int lrow = lane & 15;
#pragma unroll
    for (int kk = 0; kk < 64; kk += 32) {
      const int lk = (lane >> 4) * 8 + kk;
      bf16x8 aq[4], bq[4];
#pragma unroll
      for (int m = 0; m < 4; ++m)
        aq[m] = *(const bf16x8*)(A_lds + (size_t)(wr * 64 + m * 16 + lrow) * 64 + lk);
#pragma unroll
      for (int n = 0; n < 4; ++n)
        bq[n] = *(const bf16x8*)(B_lds + (size_t)(wc * 64 + n * 16 + lrow) * 64 + lk);
#pragma unroll
      for (int m = 0; m < 4; ++m)
#pragma unroll
        for (int n = 0; n < 4; ++n)
          acc[m][n] = __builtin_amdgcn_mfma_f32_16x16x32_bf16(aq[m], bq[n], acc[m][n], 0, 0, 0);
    }
    __syncthreads();
  }

  // ---- epilogue: exchange gates via LDS, then pointwise update ----
#pragma unroll
  for (int m = 0; m < 4; ++m) {
#pragma unroll
    for (int n = 0; n < 4; ++n) {
      int r0 = wr * 64 + m * 16 + (lane >> 4) * 4;
      int c  = wc * 64 + n * 16 + (lane & 15);
#pragma unroll
      for (int e = 0; e < 4; ++e) g_lds[(size_t)(r0 + e) * 128 + c] = acc[m][n][e];
    }
  }
  __syncthreads();

#pragma unroll 4
  for (int p = 0; p < 16; ++p) {
    int idx = p * 256 + tid;       // 0..4095 : 128 rows x 32 units
    int row = idx >> 5;
    int u   = idx & 31;
    float ig = g_lds[(size_t)row * 128 +       u] + bb[0 * H_N + j0 + u];
    float fg = g_lds[(size_t)row * 128 + 32 +  u] + bb[1 * H_N + j0 + u];
    float mg = g_lds[(size_t)row * 128 + 64 +  u] + bb[2 * H_N + j0 + u];
    float og = g_lds[(size_t)row * 128 + 96 +  u] + bb[3 * H_N + j0 + u];
    float i_ = sigmoid_(ig);
    float f_ = sigmoid_(fg);
    float m_ = tanh_(mg);
    float o_ = sigmoid_(og);
    int gi = (bm0 + row) * H_N + j0 + u;
    float cn = f_ * c_buf[gi] + i_ * m_;
    c_buf[gi] = cn;
    h_out[gi] = (bf16_t)(o_ * tanh_(cn));
  }
}

// ---------- final projection: out = h_last @ Wout^T + bout ----------
__global__ __launch_bounds__(256, 2) void out_gemm(
    const bf16_t* __restrict__ h,     // [B][H]
    const bf16_t* __restrict__ Wb,    // [O][H]
    const float*  __restrict__ bout,  // [O]
    float* __restrict__ out) {        // [B][O]
  __shared__ char smem[16384 + 8192];
  bf16_t* A_lds = (bf16_t*)smem;            // [128][64]
  bf16_t* B_lds = (bf16_t*)(smem + 16384);  // [64][64]

  const int tid = threadIdx.x, wid = tid >> 6, lane = tid & 63;
  const int bm0 = blockIdx.x * 128;
  const int n0  = blockIdx.y * 64;
  const int wr = wid >> 1, wc = wid & 1;    // wave: 64 rows x 32 cols

  f32x4 acc[4][2];
#pragma unroll
  for (int m = 0; m < 4; ++m)
#pragma unroll
    for (int n = 0; n < 2; ++n)
#pragma unroll
      for (int e = 0; e < 4; ++e) acc[m][n][e] = 0.0f;

  const int srow = tid >> 3;
  const int scol = (tid & 7) * 8;

  for (int kt = 0; kt < 16; ++kt) {
    const int k0 = kt * 64;
#pragma unroll
    for (int it = 0; it < 4; ++it) {
      const bf16_t* gp = h + (size_t)(bm0 + it * 32 + srow) * H_N + k0 + scol;
      gload16(gp, (char*)A_lds + (size_t)(it * 2048 + wid * 512) * 2);
    }
#pragma unroll
    for (int it = 0; it < 2; ++it) {
      const bf16_t* gp = Wb + (size_t)(n0 + it * 32 + srow) * H_N + k0 + scol;
      gload16(gp, (char*)B_lds + (size_t)(it * 2048 + wid * 512) * 2);
    }
    __syncthreads();

    const int lrow = lane & 15;
#pragma unroll
    for (int kk = 0; kk < 64; kk += 32) {
      const int lk = (lane >> 4) * 8 + kk;
      bf16x8 aq[4], bq[2];
#pragma unroll
      for (int m = 0; m < 4; ++m)
        aq[m] = *(const bf16x8*)(A_lds + (size_t)(wr * 64 + m * 16 + lrow) * 64 + lk);
#pragma unroll
      for (int n = 0; n < 2; ++n)
        bq[n] = *(const bf16x8*)(B_lds + (size_t)(wc * 32 + n * 16 + lrow) * 64 + lk);
#pragma unroll
      for (int m = 0; m < 4; ++m)
#pragma unroll
        for (int n = 0; n < 2; ++n)
          acc[m][n] = __builtin_amdgcn_mfma_f32_16x16x32_bf16(aq[m], bq[n], acc[m][n], 0, 0, 0);
    }
    __syncthreads();
  }

#pragma unroll
  for (int m = 0; m < 4; ++m)
#pragma unroll
    for (int n = 0; n < 2; ++n)
#pragma unroll
      for (int e = 0; e < 4; ++e) {
        int row = bm0 + wr * 64 + m * 16 + (lane >> 4) * 4 + e;
        int col = n0 + wc * 32 + n * 16 + (lane & 15);
        out[(size_t)row * O_N + col] = acc[m][n][e] + bout[col];
      }
}

// ---------- launch ----------
extern "C" void kernel_launch(void* const* d_in, const int* in_sizes, int n_in,
                              void* d_out, int out_size, void* d_ws, size_t ws_size,
                              hipStream_t stream) {
  const float* seq  = (const float*)d_in[0];
  const float* Wf_x = (const float*)d_in[1];
  const float* bf_  = (const float*)d_in[2];
  const float* Wf_h = (const float*)d_in[3];
  const float* Wi_x = (const float*)d_in[4];
  const float* bi   = (const float*)d_in[5];
  const float* Wi_h = (const float*)d_in[6];
  const float* Wm_x = (const float*)d_in[7];
  const float* bm   = (const float*)d_in[8];
  const float* Wm_h = (const float*)d_in[9];
  const float* Wo_x = (const float*)d_in[10];
  const float* bo   = (const float*)d_in[11];
  const float* Wo_h = (const float*)d_in[12];
  const float* Wout = (const float*)d_in[13];
  const float* bout = (const float*)d_in[14];
  float* out = (float*)d_out;

  char* ws = (char*)d_ws;
  size_t off = 0;
  auto alloc = [&](size_t bytes) -> void* {
    void* p = ws + off;
    off = (off + bytes + 255) & ~(size_t)255;
    return p;
  };
  bf16_t* Bmat   = (bf16_t*)alloc((size_t)NG * KTOT * 2);     // 8.9 MB
  float*  bb_all = (float*) alloc((size_t)NG * 4);            // 16 KB
  bf16_t* Woutb  = (bf16_t*)alloc((size_t)O_N * H_N * 2);     // 512 KB
  bf16_t* seqb   = (bf16_t*)alloc((size_t)B_N * T_N * I_N * 2); // 24 MB
  bf16_t* hbuf0  = (bf16_t*)alloc((size_t)B_N * H_N * 2);     // 4 MB
  bf16_t* hbuf1  = (bf16_t*)alloc((size_t)B_N * H_N * 2);     // 4 MB
  float*  cbuf   = (float*) alloc((size_t)B_N * H_N * 4);     // 8 MB

  prep_weights<<<(NG * KTOT + 255) / 256, 256, 0, stream>>>(
      Wi_h, Wf_h, Wm_h, Wo_h, Wi_x, Wf_x, Wm_x, Wo_x, Bmat);
  prep_misc<<<(O_N * H_N + 255) / 256, 256, 0, stream>>>(
      bi, bf_, bm, bo, Wout, bb_all, Woutb);
  prep_seq<<<((B_N * T_N * I_N / 4) + 255) / 256, 256, 0, stream>>>(
      (const float4*)seq, seqb, hbuf0, cbuf);

  bf16_t* hb[2] = {hbuf0, hbuf1};
  for (int t = 0; t < T_N; ++t) {
    lstm_step<<<512, 256, 0, stream>>>(Bmat, bb_all, seqb,
                                       hb[t & 1], hb[(t + 1) & 1], cbuf, t);
  }
  // after t=95 the freshest h is in hbuf0
  out_gemm<<<dim3(16, 4), 256, 0, stream>>>(hbuf0, Woutb, bout, out);
}

// Round 2
// 2475.560 us; speedup vs baseline: 1.3613x; 1.3613x over previous
//
#include <hip/hip_runtime.h>
#include <hip/hip_bf16.h>
#include <stdint.h>

typedef __bf16 bf16_t;
typedef __attribute__((ext_vector_type(8))) __bf16 bf16x8;
typedef __attribute__((ext_vector_type(4))) float f32x4;

#define B_N 2048
#define T_N 96
#define I_N 64
#define H_N 1024
#define O_N 256
#define KTOT 1088   /* H + I */
#define NG   4096   /* 4*H  */

// ---------- helpers ----------
__device__ __forceinline__ void gload16(const void* g, void* l) {
  // global -> LDS direct, 16B per lane. LDS dest must be wave-uniform base
  // (HW adds lane*16). Global source IS per-lane -> we pre-swizzle it.
  __builtin_amdgcn_global_load_lds(
      (const __attribute__((address_space(1))) uint32_t*)(uintptr_t)g,
      (__attribute__((address_space(3))) uint32_t*)(uintptr_t)l,
      16, 0, 0);
}

__device__ __forceinline__ float sigmoid_(float x) {
  return 1.0f / (1.0f + __expf(-x));
}
__device__ __forceinline__ float tanh_(float x) {
  float ax = fabsf(x);
  float e  = __expf(-2.0f * ax);     // (0,1], never overflows
  float t  = (1.0f - e) / (1.0f + e);
  return copysignf(t, x);
}

// ---------- prep kernels ----------
__global__ void prep_weights(const float* __restrict__ Wi_h, const float* __restrict__ Wf_h,
                             const float* __restrict__ Wm_h, const float* __restrict__ Wo_h,
                             const float* __restrict__ Wi_x, const float* __restrict__ Wf_x,
                             const float* __restrict__ Wm_x, const float* __restrict__ Wo_x,
                             bf16_t* __restrict__ Bmat) {
  int idx = blockIdx.x * blockDim.x + threadIdx.x;
  const int total = NG * KTOT;
  if (idx >= total) return;
  int r = idx / KTOT;
  int k = idx - r * KTOT;
  int gate = r >> 10;       // 0:i 1:f 2:m 3:o
  int j    = r & 1023;
  const float* Wh[4] = {Wi_h, Wf_h, Wm_h, Wo_h};
  const float* Wx[4] = {Wi_x, Wf_x, Wm_x, Wo_x};
  float v = (k < H_N) ? Wh[gate][j * H_N + k] : Wx[gate][j * I_N + (k - H_N)];
  Bmat[idx] = (bf16_t)v;
}

__global__ void prep_misc(const float* __restrict__ bi, const float* __restrict__ bf_,
                          const float* __restrict__ bm, const float* __restrict__ bo,
                          const float* __restrict__ Wout, float* __restrict__ bb_all,
                          bf16_t* __restrict__ Wout_b) {
  int idx = blockIdx.x * blockDim.x + threadIdx.x;
  if (idx < NG) {
    int gate = idx >> 10, j = idx & 1023;
    const float* bp[4] = {bi, bf_, bm, bo};
    bb_all[idx] = bp[gate][j];
  }
  if (idx < O_N * H_N) Wout_b[idx] = (bf16_t)Wout[idx];
}

__global__ void prep_seq(const float4* __restrict__ seq4, bf16_t* __restrict__ seqb,
                         bf16_t* __restrict__ h0, float* __restrict__ c0) {
  int idx = blockIdx.x * blockDim.x + threadIdx.x;
  const int n4 = (B_N * T_N * I_N) / 4;
  if (idx < n4) {
    float4 v = seq4[idx];
    union { bf16_t b[4]; uint2 u; } pk;
    pk.b[0] = (bf16_t)v.x; pk.b[1] = (bf16_t)v.y;
    pk.b[2] = (bf16_t)v.z; pk.b[3] = (bf16_t)v.w;
    *reinterpret_cast<uint2*>(seqb + (size_t)idx * 4) = pk.u;
  }
  const int nh = B_N * H_N;
  if (idx < nh) {
    h0[idx] = (bf16_t)0.0f;
    c0[idx] = 0.0f;
  }
}

// ---------- fused LSTM step ----------
// g = [h | x_t] @ W'^T + b ; gates ; c,h update.
// Block: 128 batch rows x 128 output cols (32 units x 4 gates).
// Double-buffered LDS (T3-minimum 2-phase: stage next tile, compute current,
// one __syncthreads per K-tile). T2 source-pre-swizzle kills the 16-way
// bank conflict on ds_read_b128 (chunk ^= row&7, applied on BOTH global
// source and LDS read address; LDS dest of global_load_lds stays linear).
__global__ __launch_bounds__(256, 2) void lstm_step(
    const bf16_t* __restrict__ Bmat,   // [4H][KTOT]
    const float*  __restrict__ bb,     // [4H]
    const bf16_t* __restrict__ seqb,   // [B][T][I]
    const bf16_t* __restrict__ h_in,   // [B][H]
    bf16_t* __restrict__ h_out,        // [B][H]
    float*  __restrict__ c_buf,        // [B][H]
    int t) {
  // A bufs: [0,16K) [16K,32K); B bufs: [32K,48K) [48K,64K).
  // Epilogue reuses smem as float[128][129] = 66048 B.
  __shared__ char smem[66048];

  const int tid  = threadIdx.x;
  const int wid  = tid >> 6;
  const int lane = tid & 63;

  // XCD-rect swizzle: 8 XCDs as 2x4 chunks of the 16x32 (bx,by) grid.
  const int bid = blockIdx.x;                 // 0..511
  const int xcd = bid & 7;
  const int r   = bid >> 3;                   // 0..63
  const int bx  = (xcd & 1) * 8 + (r & 7);    // 0..15 (M group)
  const int by  = (xcd >> 1) * 8 + (r >> 3);  // 0..31 (unit group)

  const int bm0 = bx * 128;
  const int j0  = by * 32;

  const int wr = wid >> 1, wc = wid & 1;      // wave covers 64x64 of 128x128

  f32x4 acc[4][4];
#pragma unroll
  for (int m = 0; m < 4; ++m)
#pragma unroll
    for (int n = 0; n < 4; ++n)
#pragma unroll
      for (int e = 0; e < 4; ++e) acc[m][n][e] = 0.0f;

  const int srow = tid >> 3;                    // 0..31
  const int cs   = ((tid & 7) ^ (srow & 7)) * 8; // swizzled source chunk (elems)

  // virtual B rows for the 4 staging chunks: n = it*32 + srow in 0..127
  int brow[4];
#pragma unroll
  for (int it = 0; it < 4; ++it) {
    int n = it * 32 + srow;
    int gate = n >> 5, u = n & 31;
    brow[it] = (gate << 10) + j0 + u;
  }

  auto stage = [&](int b, int s) {
    char* Ab = smem + b * 16384;
    char* Bb = smem + 32768 + b * 16384;
    if (s < 16) {
      const int k0 = s * 64;
#pragma unroll
      for (int it = 0; it < 4; ++it)
        gload16(h_in + (size_t)(bm0 + it * 32 + srow) * H_N + k0 + cs,
                Ab + it * 4096 + wid * 1024);
    } else {
#pragma unroll
      for (int it = 0; it < 4; ++it)
        gload16(seqb + (size_t)(bm0 + it * 32 + srow) * (T_N * I_N) + t * I_N + cs,
                Ab + it * 4096 + wid * 1024);
    }
    const int k0b = (s < 16) ? s * 64 : H_N;
#pragma unroll
    for (int it = 0; it < 4; ++it)
      gload16(Bmat + (size_t)brow[it] * KTOT + k0b + cs,
              Bb + it * 4096 + wid * 1024);
  };

  stage(0, 0);
  __syncthreads();          // prologue: tile 0 ready (vmcnt drained by sync)

  int cur = 0;
  const int lrow = lane & 15;
  for (int kt = 0; kt < 17; ++kt) {
    if (kt < 16) stage(cur ^ 1, kt + 1);   // issue next-tile loads NOW

    const bf16_t* Abuf = (const bf16_t*)(smem + cur * 16384);
    const bf16_t* Bbuf = (const bf16_t*)(smem + 32768 + cur * 16384);
#pragma unroll
    for (int kh = 0; kh < 2; ++kh) {
      const int cc = (lane >> 4) + kh * 4;          // data chunk 0..7
      const int so = ((cc ^ (lrow & 7)) << 3);      // swizzled slot (elems)
      bf16x8 aq[4], bq[4];
#pragma unroll
      for (int m = 0; m < 4; ++m)
        aq[m] = *(const bf16x8*)(Abuf + (size_t)(wr * 64 + m * 16 + lrow) * 64 + so);
#pragma unroll
      for (int n = 0; n < 4; ++n)
        bq[n] = *(const bf16x8*)(Bbuf + (size_t)(wc * 64 + n * 16 + lrow) * 64 + so);
#pragma unroll
      for (int m = 0; m < 4; ++m)
#pragma unroll
        for (int n = 0; n < 4; ++n)
          acc[m][n] = __builtin_amdgcn_mfma_f32_16x16x32_bf16(aq[m], bq[n], acc[m][n], 0, 0, 0);
    }
    __syncthreads();   // drains vmcnt (next tile landed) + all reads of cur done
    cur ^= 1;
  }

  // ---- epilogue: exchange gates via LDS (stride 129: conflict-free), update ----
  float* g_lds = (float*)smem;   // [128][129]
#pragma unroll
  for (int m = 0; m < 4; ++m) {
#pragma unroll
    for (int n = 0; n < 4; ++n) {
      int r0 = wr * 64 + m * 16 + (lane >> 4) * 4;
      int c  = wc * 64 + n * 16 + (lane & 15);
#pragma unroll
      for (int e = 0; e < 4; ++e) g_lds[(size_t)(r0 + e) * 129 + c] = acc[m][n][e];
    }
  }
  __syncthreads();

#pragma unroll 4
  for (int p = 0; p < 16; ++p) {
    int idx = p * 256 + tid;       // 0..4095 : 128 rows x 32 units
    int row = idx >> 5;
    int u   = idx & 31;
    float ig = g_lds[(size_t)row * 129 +       u] + bb[0 * H_N + j0 + u];
    float fg = g_lds[(size_t)row * 129 + 32 +  u] + bb[1 * H_N + j0 + u];
    float mg = g_lds[(size_t)row * 129 + 64 +  u] + bb[2 * H_N + j0 + u];
    float og = g_lds[(size_t)row * 129 + 96 +  u] + bb[3 * H_N + j0 + u];
    float i_ = sigmoid_(ig);
    float f_ = sigmoid_(fg);
    float m_ = tanh_(mg);
    float o_ = sigmoid_(og);
    int gi = (bm0 + row) * H_N + j0 + u;
    float cn = f_ * c_buf[gi] + i_ * m_;
    c_buf[gi] = cn;
    h_out[gi] = (bf16_t)(o_ * tanh_(cn));
  }
}

// ---------- final projection: out = h_last @ Wout^T + bout ----------
__global__ __launch_bounds__(256, 2) void out_gemm(
    const bf16_t* __restrict__ h,     // [B][H]
    const bf16_t* __restrict__ Wb,    // [O][H]
    const float*  __restrict__ bout,  // [O]
    float* __restrict__ out) {        // [B][O]
  __shared__ char smem[16384 + 8192];
  bf16_t* A_lds = (bf16_t*)smem;            // [128][64]
  bf16_t* B_lds = (bf16_t*)(smem + 16384);  // [64][64]

  const int tid = threadIdx.x, wid = tid >> 6, lane = tid & 63;
  const int bm0 = blockIdx.x * 128;
  const int n0  = blockIdx.y * 64;
  const int wr = wid >> 1, wc = wid & 1;    // wave: 64 rows x 32 cols

  f32x4 acc[4][2];
#pragma unroll
  for (int m = 0; m < 4; ++m)
#pragma unroll
    for (int n = 0; n < 2; ++n)
#pragma unroll
      for (int e = 0; e < 4; ++e) acc[m][n][e] = 0.0f;

  const int srow = tid >> 3;
  const int scol = (tid & 7) * 8;

  for (int kt = 0; kt < 16; ++kt) {
    const int k0 = kt * 64;
#pragma unroll
    for (int it = 0; it < 4; ++it) {
      const bf16_t* gp = h + (size_t)(bm0 + it * 32 + srow) * H_N + k0 + scol;
      gload16(gp, (char*)A_lds + (size_t)(it * 2048 + wid * 512) * 2);
    }
#pragma unroll
    for (int it = 0; it < 2; ++it) {
      const bf16_t* gp = Wb + (size_t)(n0 + it * 32 + srow) * H_N + k0 + scol;
      gload16(gp, (char*)B_lds + (size_t)(it * 2048 + wid * 512) * 2);
    }
    __syncthreads();

    const int lrow = lane & 15;
#pragma unroll
    for (int kk = 0; kk < 64; kk += 32) {
      const int lk = (lane >> 4) * 8 + kk;
      bf16x8 aq[4], bq[2];
#pragma unroll
      for (int m = 0; m < 4; ++m)
        aq[m] = *(const bf16x8*)(A_lds + (size_t)(wr * 64 + m * 16 + lrow) * 64 + lk);
#pragma unroll
      for (int n = 0; n < 2; ++n)
        bq[n] = *(const bf16x8*)(B_lds + (size_t)(wc * 32 + n * 16 + lrow) * 64 + lk);
#pragma unroll
      for (int m = 0; m < 4; ++m)
#pragma unroll
        for (int n = 0; n < 2; ++n)
          acc[m][n] = __builtin_amdgcn_mfma_f32_16x16x32_bf16(aq[m], bq[n], acc[m][n], 0, 0, 0);
    }
    __syncthreads();
  }

#pragma unroll
  for (int m = 0; m < 4; ++m)
#pragma unroll
    for (int n = 0; n < 2; ++n)
#pragma unroll
      for (int e = 0; e < 4; ++e) {
        int row = bm0 + wr * 64 + m * 16 + (lane >> 4) * 4 + e;
        int col = n0 + wc * 32 + n * 16 + (lane & 15);
        out[(size_t)row * O_N + col] = acc[m][n][e] + bout[col];
      }
}

// ---------- launch ----------
extern "C" void kernel_launch(void* const* d_in, const int* in_sizes, int n_in,
                              void* d_out, int out_size, void* d_ws, size_t ws_size,
                              hipStream_t stream) {
  const float* seq  = (const float*)d_in[0];
  const float* Wf_x = (const float*)d_in[1];
  const float* bf_  = (const float*)d_in[2];
  const float* Wf_h = (const float*)d_in[3];
  const float* Wi_x = (const float*)d_in[4];
  const float* bi   = (const float*)d_in[5];
  const float* Wi_h = (const float*)d_in[6];
  const float* Wm_x = (const float*)d_in[7];
  const float* bm   = (const float*)d_in[8];
  const float* Wm_h = (const float*)d_in[9];
  const float* Wo_x = (const float*)d_in[10];
  const float* bo   = (const float*)d_in[11];
  const float* Wo_h = (const float*)d_in[12];
  const float* Wout = (const float*)d_in[13];
  const float* bout = (const float*)d_in[14];
  float* out = (float*)d_out;

  char* ws = (char*)d_ws;
  size_t off = 0;
  auto alloc = [&](size_t bytes) -> void* {
    void* p = ws + off;
    off = (off + bytes + 255) & ~(size_t)255;
    return p;
  };
  bf16_t* Bmat   = (bf16_t*)alloc((size_t)NG * KTOT * 2);     // 8.9 MB
  float*  bb_all = (float*) alloc((size_t)NG * 4);            // 16 KB
  bf16_t* Woutb  = (bf16_t*)alloc((size_t)O_N * H_N * 2);     // 512 KB
  bf16_t* seqb   = (bf16_t*)alloc((size_t)B_N * T_N * I_N * 2); // 24 MB
  bf16_t* hbuf0  = (bf16_t*)alloc((size_t)B_N * H_N * 2);     // 4 MB
  bf16_t* hbuf1  = (bf16_t*)alloc((size_t)B_N * H_N * 2);     // 4 MB
  float*  cbuf   = (float*) alloc((size_t)B_N * H_N * 4);     // 8 MB

  prep_weights<<<(NG * KTOT + 255) / 256, 256, 0, stream>>>(
      Wi_h, Wf_h, Wm_h, Wo_h, Wi_x, Wf_x, Wm_x, Wo_x, Bmat);
  prep_misc<<<(O_N * H_N + 255) / 256, 256, 0, stream>>>(
      bi, bf_, bm, bo, Wout, bb_all, Woutb);
  prep_seq<<<((B_N * T_N * I_N / 4) + 255) / 256, 256, 0, stream>>>(
      (const float4*)seq, seqb, hbuf0, cbuf);

  bf16_t* hb[2] = {hbuf0, hbuf1};
  for (int t = 0; t < T_N; ++t) {
    lstm_step<<<512, 256, 0, stream>>>(Bmat, bb_all, seqb,
                                       hb[t & 1], hb[(t + 1) & 1], cbuf, t);
  }
  // after t=95 the freshest h is in hbuf0
  out_gemm<<<dim3(16, 4), 256, 0, stream>>>(hbuf0, Woutb, bout, out);
}